// Round 3
// baseline (1829.722 us; speedup 1.0000x reference)
//
#include <hip/hip_runtime.h>
#include <hip/hip_bf16.h>

#define D 128
#define KTOP 3
#define NCLS 10
#define EPS 1e-5f
#define BM 64

// ---------------- degree / CSR build ----------------

__global__ void deg_kernel(const int* __restrict__ src, const int* __restrict__ dst,
                           int* __restrict__ deg_out, int* __restrict__ deg_in, int E) {
    int e = blockIdx.x * blockDim.x + threadIdx.x;
    if (e >= E) return;
    atomicAdd(&deg_out[src[e]], 1);
    atomicAdd(&deg_in[dst[e]], 1);
}

__global__ void rs_kernel(const int* __restrict__ deg_out, const int* __restrict__ deg_in,
                          float* __restrict__ rs_out, float* __restrict__ rs_in, int N) {
    int i = blockIdx.x * blockDim.x + threadIdx.x;
    if (i >= N) return;
    int a = deg_out[i]; if (a < 1) a = 1;
    int b = deg_in[i];  if (b < 1) b = 1;
    rs_out[i] = rsqrtf((float)a);
    rs_in[i]  = rsqrtf((float)b);
}

// single-block exclusive scan of deg_in -> offs[0..N], offs[N]=E
__global__ __launch_bounds__(1024) void scan_kernel(const int* __restrict__ deg,
                                                    int* __restrict__ offs, int N) {
    __shared__ int part[1024];
    int t = threadIdx.x;
    int per = (N + 1023) >> 10;
    int beg = t * per;
    int end = beg + per; if (end > N) end = N;
    int s = 0;
    for (int i = beg; i < end; ++i) s += deg[i];
    part[t] = s;
    __syncthreads();
    for (int off = 1; off < 1024; off <<= 1) {
        int v = (t >= off) ? part[t - off] : 0;
        __syncthreads();
        part[t] += v;
        __syncthreads();
    }
    int run = (t == 0) ? 0 : part[t - 1];
    for (int i = beg; i < end; ++i) { offs[i] = run; run += deg[i]; }
    if (t == 1023) offs[N] = run;
}

// writes {src, bits(rs_out[src])} so the gather needs ONE 8B load per edge
__global__ void csr_scatter(const int* __restrict__ src, const int* __restrict__ dst,
                            const float* __restrict__ rs_out,
                            const int* __restrict__ offs, int* __restrict__ cursor,
                            int2* __restrict__ csrw, int E) {
    int e = blockIdx.x * blockDim.x + threadIdx.x;
    if (e >= E) return;
    int d = dst[e], s = src[e];
    int pos = offs[d] + atomicAdd(&cursor[d], 1);
    int2 p; p.x = s; p.y = __float_as_int(rs_out[s]);
    csrw[pos] = p;
}

// ---------------- aggregation: one wave per dst node, 4 rows in flight ----------------

__global__ __launch_bounds__(256) void aggregate_kernel(const float* __restrict__ hin,
        const int* __restrict__ offs, const int2* __restrict__ csrw,
        const float* __restrict__ rs_in, float* __restrict__ hout, int N) {
    int wv   = (blockIdx.x * 256 + threadIdx.x) >> 6;
    int lane = threadIdx.x & 63;
    if (wv >= N) return;
    int beg = offs[wv], end = offs[wv + 1];
    const float* base = hin + 2 * lane;
    float ax0=0.f, ay0=0.f, ax1=0.f, ay1=0.f, ax2=0.f, ay2=0.f, ax3=0.f, ay3=0.f;
    int nq = (end - beg) >> 2;
    int e = beg;
    int2 c0, c1, c2, c3;
    if (nq) { c0 = csrw[e]; c1 = csrw[e+1]; c2 = csrw[e+2]; c3 = csrw[e+3]; }
    for (int q = 0; q < nq; ++q) {
        int2 n0 = c0, n1 = c1, n2 = c2, n3 = c3;
        int en = e + 4;
        if (q + 1 < nq) { n0 = csrw[en]; n1 = csrw[en+1]; n2 = csrw[en+2]; n3 = csrw[en+3]; }
        float2 v0 = *reinterpret_cast<const float2*>(base + (size_t)c0.x * D);
        float2 v1 = *reinterpret_cast<const float2*>(base + (size_t)c1.x * D);
        float2 v2 = *reinterpret_cast<const float2*>(base + (size_t)c2.x * D);
        float2 v3 = *reinterpret_cast<const float2*>(base + (size_t)c3.x * D);
        float w0 = __int_as_float(c0.y), w1 = __int_as_float(c1.y);
        float w2 = __int_as_float(c2.y), w3 = __int_as_float(c3.y);
        ax0 += w0 * v0.x; ay0 += w0 * v0.y;
        ax1 += w1 * v1.x; ay1 += w1 * v1.y;
        ax2 += w2 * v2.x; ay2 += w2 * v2.y;
        ax3 += w3 * v3.x; ay3 += w3 * v3.y;
        c0 = n0; c1 = n1; c2 = n2; c3 = n3;
        e = en;
    }
    for (; e < end; ++e) {
        int2 c = csrw[e];
        float w = __int_as_float(c.y);
        float2 v = *reinterpret_cast<const float2*>(base + (size_t)c.x * D);
        ax0 += w * v.x; ay0 += w * v.y;
    }
    float ri = rs_in[wv];
    float2 r;
    r.x = ((ax0 + ax1) + (ax2 + ax3)) * ri;
    r.y = ((ay0 + ay1) + (ay2 + ay3)) * ri;
    *reinterpret_cast<float2*>(hout + (size_t)wv * D + 2 * lane) = r;
}

// ---------------- GEMM (out-of-place) + bias + fused BN-stats ----------------

__global__ __launch_bounds__(256) void gemm_bn(const float* __restrict__ ain,
        const float* __restrict__ W, const float* __restrict__ bias,
        float* __restrict__ hout, float* __restrict__ bnsums, int N) {
    __shared__ __align__(16) float At[D][BM];   // swizzled transposed A [k][m]
    __shared__ __align__(16) float Wl[32][D];   // W chunk [k][c]
    int t = threadIdx.x;
    size_t rowBase = (size_t)blockIdx.x * BM;

    // stage A: coalesced float4 global reads, swizzled transpose into LDS
#pragma unroll
    for (int it = 0; it < 8; ++it) {
        int i = t + 256 * it;
        int m = i >> 5, k4 = i & 31;
        float4 v = *reinterpret_cast<const float4*>(ain + (rowBase + m) * D + 4 * k4);
        int cg = (m >> 2) ^ (k4 & 15);
        int co = cg * 4 + (m & 3);
        At[4*k4 + 0][co] = v.x;
        At[4*k4 + 1][co] = v.y;
        At[4*k4 + 2][co] = v.z;
        At[4*k4 + 3][co] = v.w;
    }

    int tx = t & 15, ty = t >> 4;
    int r0 = tx * 4, c0 = ty * 8;
    float acc[4][8];
#pragma unroll
    for (int i = 0; i < 4; ++i)
#pragma unroll
        for (int j = 0; j < 8; ++j) acc[i][j] = 0.f;

    for (int kc = 0; kc < D; kc += 32) {
        __syncthreads();
        const float4* Wv = reinterpret_cast<const float4*>(W + (size_t)kc * D);
        float4* Wd = reinterpret_cast<float4*>(&Wl[0][0]);
        for (int i = t; i < 32 * D / 4; i += 256) Wd[i] = Wv[i];
        __syncthreads();
#pragma unroll 8
        for (int k = 0; k < 32; ++k) {
            int kk = kc + k;
            float4 av4 = *reinterpret_cast<const float4*>(&At[kk][(tx ^ ((kk >> 2) & 15)) << 2]);
            float4 w0 = *reinterpret_cast<const float4*>(&Wl[k][c0]);
            float4 w1 = *reinterpret_cast<const float4*>(&Wl[k][c0 + 4]);
            float av[4] = {av4.x, av4.y, av4.z, av4.w};
            float wv[8] = {w0.x, w0.y, w0.z, w0.w, w1.x, w1.y, w1.z, w1.w};
#pragma unroll
            for (int i = 0; i < 4; ++i)
#pragma unroll
                for (int j = 0; j < 8; ++j) acc[i][j] += av[i] * wv[j];
        }
    }

    float4 b0 = *reinterpret_cast<const float4*>(&bias[c0]);
    float4 b1 = *reinterpret_cast<const float4*>(&bias[c0 + 4]);
    float bv[8] = {b0.x, b0.y, b0.z, b0.w, b1.x, b1.y, b1.z, b1.w};
    float cs[8], cq[8];
#pragma unroll
    for (int j = 0; j < 8; ++j) { cs[j] = 0.f; cq[j] = 0.f; }
#pragma unroll
    for (int i = 0; i < 4; ++i) {
#pragma unroll
        for (int j = 0; j < 8; ++j) {
            float v = acc[i][j] + bv[j];
            acc[i][j] = v;
            cs[j] += v;
            cq[j] += v * v;
        }
    }
#pragma unroll
    for (int i = 0; i < 4; ++i) {
        size_t row = rowBase + r0 + i;
        float4 o0, o1;
        o0.x = acc[i][0]; o0.y = acc[i][1]; o0.z = acc[i][2]; o0.w = acc[i][3];
        o1.x = acc[i][4]; o1.y = acc[i][5]; o1.z = acc[i][6]; o1.w = acc[i][7];
        *reinterpret_cast<float4*>(&hout[row * D + c0])     = o0;
        *reinterpret_cast<float4*>(&hout[row * D + c0 + 4]) = o1;
    }
#pragma unroll
    for (int o = 1; o < 16; o <<= 1) {
#pragma unroll
        for (int j = 0; j < 8; ++j) {
            cs[j] += __shfl_xor(cs[j], o, 64);
            cq[j] += __shfl_xor(cq[j], o, 64);
        }
    }
    if (tx == 0) {
#pragma unroll
        for (int j = 0; j < 8; ++j) {
            atomicAdd(&bnsums[c0 + j], cs[j]);
            atomicAdd(&bnsums[D + c0 + j], cq[j]);
        }
    }
}

// ---------------- BatchNorm finalize + apply ----------------

__global__ void bn_final(const float* __restrict__ sums, const float* __restrict__ g,
                         const float* __restrict__ bt, float* __restrict__ sc,
                         float* __restrict__ sh, int N) {
    int c = threadIdx.x;
    if (c >= D) return;
    float mu  = sums[c] / (float)N;
    float var = sums[D + c] / (float)N - mu * mu;
    float inv = rsqrtf(var + EPS);
    float scale = g[c] * inv;
    sc[c] = scale;
    sh[c] = bt[c] - mu * scale;
}

__global__ __launch_bounds__(256) void bn_apply_relu_max(float* __restrict__ h,
        const float* __restrict__ sc, const float* __restrict__ sh,
        float* __restrict__ nodemax, int N) {
    int node = (blockIdx.x * 256 + threadIdx.x) >> 5;
    int l = threadIdx.x & 31;
    if (node >= N) return;
    float4 v = *reinterpret_cast<const float4*>(h + (size_t)node * D + 4 * l);
    float4 a = *reinterpret_cast<const float4*>(sc + 4 * l);
    float4 b = *reinterpret_cast<const float4*>(sh + 4 * l);
    v.x = fmaxf(fmaf(v.x, a.x, b.x), 0.f);
    v.y = fmaxf(fmaf(v.y, a.y, b.y), 0.f);
    v.z = fmaxf(fmaf(v.z, a.z, b.z), 0.f);
    v.w = fmaxf(fmaf(v.w, a.w, b.w), 0.f);
    *reinterpret_cast<float4*>(h + (size_t)node * D + 4 * l) = v;
    float m = fmaxf(fmaxf(v.x, v.y), fmaxf(v.z, v.w));
#pragma unroll
    for (int d = 16; d > 0; d >>= 1) m = fmaxf(m, __shfl_xor(m, d, 64));
    if (l == 0) nodemax[node] = m;
}

__global__ __launch_bounds__(256) void rowmax_kernel(const float* __restrict__ h,
                                                     float* __restrict__ nodemax, int N) {
    int node = (blockIdx.x * 256 + threadIdx.x) >> 5;
    int l = threadIdx.x & 31;
    if (node >= N) return;
    float4 v = *reinterpret_cast<const float4*>(h + (size_t)node * D + 4 * l);
    float m = fmaxf(fmaxf(v.x, v.y), fmaxf(v.z, v.w));
#pragma unroll
    for (int d = 16; d > 0; d >>= 1) m = fmaxf(m, __shfl_xor(m, d, 64));
    if (l == 0) nodemax[node] = m;
}

// ---------------- SortPool top-k + head ----------------

__global__ __launch_bounds__(256) void topk_kernel(const float* __restrict__ nodemax,
                                                   int* __restrict__ tk, int NPG) {
    int g = blockIdx.x;
    int t = threadIdx.x;
    __shared__ float ov[256];
    __shared__ float sv[256];
    __shared__ int   si[256];
    ov[t] = (t < NPG) ? nodemax[(size_t)g * NPG + t] : -3.4e38f;
    __syncthreads();
    for (int sel = 0; sel < 3; ++sel) {
        sv[t] = ov[t]; si[t] = t;
        __syncthreads();
        for (int s = 128; s > 0; s >>= 1) {
            if (t < s) {
                float a = sv[t], b = sv[t + s];
                int ia = si[t], ib = si[t + s];
                if (b > a || (b == a && ib < ia)) { sv[t] = b; si[t] = ib; }
            }
            __syncthreads();
        }
        if (t == 0) {
            tk[g * 3 + sel] = g * NPG + si[0];
            ov[si[0]] = -3.4e38f;
        }
        __syncthreads();
    }
}

__global__ void score_init(float* __restrict__ score, const float* __restrict__ b0,
                           const float* __restrict__ b1, const float* __restrict__ b2,
                           const float* __restrict__ b3, int G) {
    int i = blockIdx.x * blockDim.x + threadIdx.x;
    if (i >= G * NCLS) return;
    int c = i % NCLS;
    score[i] = b0[c] + b1[c] + b2[c] + b3[c];
}

// one block (128 thr) per (graph, k): sort node features asc, dot with Pw rows
__global__ __launch_bounds__(128) void sort_head(const float* __restrict__ h,
        const int* __restrict__ tk, const float* __restrict__ Pw,
        float* __restrict__ score, int G) {
    int b = blockIdx.x;
    int g = b / KTOP, k = b - g * KTOP;
    int node = tk[b];
    int t = threadIdx.x;
    __shared__ float s[D];
    __shared__ float red[2][NCLS];
    s[t] = h[(size_t)node * D + t];
    __syncthreads();
    for (int size = 2; size <= D; size <<= 1) {
        for (int stride = size >> 1; stride > 0; stride >>= 1) {
            int ixj = t ^ stride;
            if (ixj > t) {
                float a = s[t], c = s[ixj];
                bool up = ((t & size) == 0);
                if ((a > c) == up) { s[t] = c; s[ixj] = a; }
            }
            __syncthreads();
        }
    }
    float v = s[t];
    const float* pw = Pw + (size_t)(k * D + t) * NCLS;
    float part[NCLS];
#pragma unroll
    for (int c = 0; c < NCLS; ++c) part[c] = v * pw[c];
    int lane = t & 63, wid = t >> 6;
#pragma unroll
    for (int c = 0; c < NCLS; ++c) {
        float x = part[c];
#pragma unroll
        for (int o = 32; o > 0; o >>= 1) x += __shfl_down(x, o, 64);
        if (lane == 0) red[wid][c] = x;
    }
    __syncthreads();
    if (t < NCLS) atomicAdd(&score[g * NCLS + t], red[0][t] + red[1][t]);
}

// ---------------- launch ----------------

extern "C" void kernel_launch(void* const* d_in, const int* in_sizes, int n_in,
                              void* d_out, int out_size, void* d_ws, size_t ws_size,
                              hipStream_t stream) {
    const float* x   = (const float*)d_in[0];
    const int*   src = (const int*)d_in[1];
    const int*   dst = (const int*)d_in[2];
    const float* W[3]  = {(const float*)d_in[5],  (const float*)d_in[9],  (const float*)d_in[13]};
    const float* bb[3] = {(const float*)d_in[6],  (const float*)d_in[10], (const float*)d_in[14]};
    const float* gg[3] = {(const float*)d_in[7],  (const float*)d_in[11], (const float*)d_in[15]};
    const float* bt[3] = {(const float*)d_in[8],  (const float*)d_in[12], (const float*)d_in[16]};
    const float* Pw[4] = {(const float*)d_in[17], (const float*)d_in[19], (const float*)d_in[21], (const float*)d_in[23]};
    const float* Pb[4] = {(const float*)d_in[18], (const float*)d_in[20], (const float*)d_in[22], (const float*)d_in[24]};

    int N = in_sizes[0] / D;
    int E = in_sizes[1];
    int G = out_size / NCLS;
    int NPG = N / G;
    float* score = (float*)d_out;

    size_t NF = (size_t)N * D;
    float* fws     = (float*)d_ws;
    float* H       = fws;
    float* T       = H + NF;
    float* rs_out  = T + NF;
    float* rs_in   = rs_out + N;
    float* nodemax = rs_in + N;
    float* bnsums  = nodemax + N;      // 3 layers x 2*D
    float* bscale  = bnsums + 6 * D;   // D
    float* bshift  = bscale + D;       // D
    int* deg_out = (int*)(bshift + D);
    int* deg_in  = deg_out + N;
    int* cursor  = deg_in + N;
    int* offs    = cursor + N;         // N+2 (padded for int2 alignment)
    int2* csrw   = (int2*)(offs + N + 2);  // E
    int* tk      = (int*)(csrw + E);   // G*3

    hipMemsetAsync(deg_out, 0, sizeof(int) * (size_t)3 * N, stream);  // deg_out, deg_in, cursor
    hipMemsetAsync(bnsums, 0, sizeof(float) * 6 * D, stream);
    deg_kernel<<<(E + 255) / 256, 256, 0, stream>>>(src, dst, deg_out, deg_in, E);
    rs_kernel<<<(N + 255) / 256, 256, 0, stream>>>(deg_out, deg_in, rs_out, rs_in, N);
    scan_kernel<<<1, 1024, 0, stream>>>(deg_in, offs, N);
    csr_scatter<<<(E + 255) / 256, 256, 0, stream>>>(src, dst, rs_out, offs, cursor, csrw, E);

    score_init<<<(G * NCLS + 255) / 256, 256, 0, stream>>>(score, Pb[0], Pb[1], Pb[2], Pb[3], G);

    // rep 0 head (raw x)
    rowmax_kernel<<<N / 8, 256, 0, stream>>>(x, nodemax, N);
    topk_kernel<<<G, 256, 0, stream>>>(nodemax, tk, NPG);
    sort_head<<<G * KTOP, D, 0, stream>>>(x, tk, Pw[0], score, G);

    const float* hin = x;
    for (int l = 0; l < 3; ++l) {
        float* bns = bnsums + l * 2 * D;
        aggregate_kernel<<<N / 4, 256, 0, stream>>>(hin, offs, csrw, rs_in, T, N);
        gemm_bn<<<N / BM, 256, 0, stream>>>(T, W[l], bb[l], H, bns, N);
        bn_final<<<1, D, 0, stream>>>(bns, gg[l], bt[l], bscale, bshift, N);
        bn_apply_relu_max<<<N / 8, 256, 0, stream>>>(H, bscale, bshift, nodemax, N);
        topk_kernel<<<G, 256, 0, stream>>>(nodemax, tk, NPG);
        sort_head<<<G * KTOP, D, 0, stream>>>(H, tk, Pw[l + 1], score, G);
        hin = H;
    }
}

// Round 4
// 1049.631 us; speedup vs baseline: 1.7432x; 1.7432x over previous
//
#include <hip/hip_runtime.h>
#include <hip/hip_bf16.h>

#define D 128
#define KTOP 3
#define NCLS 10
#define EPS 1e-5f
#define GBM 128   // rows per gemm block

// ---------------- degree / CSR build ----------------

__global__ void deg_kernel(const int* __restrict__ src, const int* __restrict__ dst,
                           int* __restrict__ deg_out, int* __restrict__ deg_in, int E) {
    int e = blockIdx.x * blockDim.x + threadIdx.x;
    if (e >= E) return;
    atomicAdd(&deg_out[src[e]], 1);
    atomicAdd(&deg_in[dst[e]], 1);
}

__global__ void rs_kernel(const int* __restrict__ deg_out, const int* __restrict__ deg_in,
                          float* __restrict__ rs_out, float* __restrict__ rs_in, int N) {
    int i = blockIdx.x * blockDim.x + threadIdx.x;
    if (i >= N) return;
    int a = deg_out[i]; if (a < 1) a = 1;
    int b = deg_in[i];  if (b < 1) b = 1;
    rs_out[i] = rsqrtf((float)a);
    rs_in[i]  = rsqrtf((float)b);
}

__global__ __launch_bounds__(1024) void scan_kernel(const int* __restrict__ deg,
                                                    int* __restrict__ offs, int N) {
    __shared__ int part[1024];
    int t = threadIdx.x;
    int per = (N + 1023) >> 10;
    int beg = t * per;
    int end = beg + per; if (end > N) end = N;
    int s = 0;
    for (int i = beg; i < end; ++i) s += deg[i];
    part[t] = s;
    __syncthreads();
    for (int off = 1; off < 1024; off <<= 1) {
        int v = (t >= off) ? part[t - off] : 0;
        __syncthreads();
        part[t] += v;
        __syncthreads();
    }
    int run = (t == 0) ? 0 : part[t - 1];
    for (int i = beg; i < end; ++i) { offs[i] = run; run += deg[i]; }
    if (t == 1023) offs[N] = run;
}

// writes {src, bits(rs_out[src])} so the gather needs ONE 8B load per edge
__global__ void csr_scatter(const int* __restrict__ src, const int* __restrict__ dst,
                            const float* __restrict__ rs_out,
                            const int* __restrict__ offs, int* __restrict__ cursor,
                            int2* __restrict__ csrw, int E) {
    int e = blockIdx.x * blockDim.x + threadIdx.x;
    if (e >= E) return;
    int d = dst[e], s = src[e];
    int pos = offs[d] + atomicAdd(&cursor[d], 1);
    int2 p; p.x = s; p.y = __float_as_int(rs_out[s]);
    csrw[pos] = p;
}

// ---------------- aggregation: half-wave (32 lanes x float4) per node ----------------

__global__ __launch_bounds__(256) void aggregate_kernel(const float* __restrict__ hin,
        const int* __restrict__ offs, const int2* __restrict__ csrw,
        const float* __restrict__ rs_in, float* __restrict__ hout, int N) {
    int node = (blockIdx.x * 256 + threadIdx.x) >> 5;
    int l = threadIdx.x & 31;
    if (node >= N) return;
    int beg = offs[node], end = offs[node + 1];
    const float* base = hin + 4 * l;
    float ax0=0.f, ay0=0.f, az0=0.f, aw0=0.f;
    float ax1=0.f, ay1=0.f, az1=0.f, aw1=0.f;
    float ax2=0.f, ay2=0.f, az2=0.f, aw2=0.f;
    float ax3=0.f, ay3=0.f, az3=0.f, aw3=0.f;
    int nq = (end - beg) >> 2;
    int e = beg;
    int2 c0, c1, c2, c3;
    if (nq) { c0 = csrw[e]; c1 = csrw[e+1]; c2 = csrw[e+2]; c3 = csrw[e+3]; }
    for (int q = 0; q < nq; ++q) {
        int2 n0 = c0, n1 = c1, n2 = c2, n3 = c3;
        int en = e + 4;
        if (q + 1 < nq) { n0 = csrw[en]; n1 = csrw[en+1]; n2 = csrw[en+2]; n3 = csrw[en+3]; }
        float4 v0 = *reinterpret_cast<const float4*>(base + (size_t)c0.x * D);
        float4 v1 = *reinterpret_cast<const float4*>(base + (size_t)c1.x * D);
        float4 v2 = *reinterpret_cast<const float4*>(base + (size_t)c2.x * D);
        float4 v3 = *reinterpret_cast<const float4*>(base + (size_t)c3.x * D);
        float w0 = __int_as_float(c0.y), w1 = __int_as_float(c1.y);
        float w2 = __int_as_float(c2.y), w3 = __int_as_float(c3.y);
        ax0 += w0*v0.x; ay0 += w0*v0.y; az0 += w0*v0.z; aw0 += w0*v0.w;
        ax1 += w1*v1.x; ay1 += w1*v1.y; az1 += w1*v1.z; aw1 += w1*v1.w;
        ax2 += w2*v2.x; ay2 += w2*v2.y; az2 += w2*v2.z; aw2 += w2*v2.w;
        ax3 += w3*v3.x; ay3 += w3*v3.y; az3 += w3*v3.z; aw3 += w3*v3.w;
        c0 = n0; c1 = n1; c2 = n2; c3 = n3;
        e = en;
    }
    for (; e < end; ++e) {
        int2 c = csrw[e];
        float w = __int_as_float(c.y);
        float4 v = *reinterpret_cast<const float4*>(base + (size_t)c.x * D);
        ax0 += w*v.x; ay0 += w*v.y; az0 += w*v.z; aw0 += w*v.w;
    }
    float ri = rs_in[node];
    float4 r;
    r.x = ((ax0 + ax1) + (ax2 + ax3)) * ri;
    r.y = ((ay0 + ay1) + (ay2 + ay3)) * ri;
    r.z = ((az0 + az1) + (az2 + az3)) * ri;
    r.w = ((aw0 + aw1) + (aw2 + aw3)) * ri;
    *reinterpret_cast<float4*>(hout + (size_t)node * D + 4 * l) = r;
}

// ---------------- GEMM: W-in-LDS, A from global, fused bias + BN-stats ----------------
// 512 threads, 128 rows/block. Thread (cg=t&15, rs=t>>4): rows 4rs..4rs+3,
// cols 8cg..8cg+7. Lanes 0..15 of a wave share each A address (coalesced
// broadcast) -> A global traffic is 1x, L2-resident. W staged in two 32KB
// half-k chunks. 32 FMA per 2 ds_read_b128.

__global__ __launch_bounds__(512) void gemm_bn(const float* __restrict__ ain,
        const float* __restrict__ W, const float* __restrict__ bias,
        float* __restrict__ hout, float* __restrict__ bnsums, int N) {
    __shared__ __align__(16) float Wl[64][D];   // 32 KB
    int t = threadIdx.x;
    int cg = t & 15;
    int rs = t >> 4;
    int c0 = cg * 8;
    size_t rowBase = (size_t)blockIdx.x * GBM + 4 * rs;

    float acc[4][8];
#pragma unroll
    for (int i = 0; i < 4; ++i)
#pragma unroll
        for (int j = 0; j < 8; ++j) acc[i][j] = 0.f;

    for (int kc = 0; kc < D; kc += 64) {
        __syncthreads();
        const float4* Wv = reinterpret_cast<const float4*>(W + (size_t)kc * D);
        float4* Wd = reinterpret_cast<float4*>(&Wl[0][0]);
#pragma unroll
        for (int i = 0; i < 4; ++i) Wd[t + 512 * i] = Wv[t + 512 * i];
        __syncthreads();
#pragma unroll 2
        for (int k4 = 0; k4 < 16; ++k4) {
            const float* ap = ain + rowBase * D + kc + 4 * k4;
            float4 a0 = *reinterpret_cast<const float4*>(ap);
            float4 a1 = *reinterpret_cast<const float4*>(ap + D);
            float4 a2 = *reinterpret_cast<const float4*>(ap + 2 * D);
            float4 a3 = *reinterpret_cast<const float4*>(ap + 3 * D);
#pragma unroll
            for (int j = 0; j < 4; ++j) {
                int kk = 4 * k4 + j;
                float4 w0 = *reinterpret_cast<const float4*>(&Wl[kk][c0]);
                float4 w1 = *reinterpret_cast<const float4*>(&Wl[kk][c0 + 4]);
                float av[4];
                av[0] = (j==0)?a0.x:(j==1)?a0.y:(j==2)?a0.z:a0.w;
                av[1] = (j==0)?a1.x:(j==1)?a1.y:(j==2)?a1.z:a1.w;
                av[2] = (j==0)?a2.x:(j==1)?a2.y:(j==2)?a2.z:a2.w;
                av[3] = (j==0)?a3.x:(j==1)?a3.y:(j==2)?a3.z:a3.w;
                float wv[8] = {w0.x, w0.y, w0.z, w0.w, w1.x, w1.y, w1.z, w1.w};
#pragma unroll
                for (int i = 0; i < 4; ++i)
#pragma unroll
                    for (int jj = 0; jj < 8; ++jj) acc[i][jj] += av[i] * wv[jj];
            }
        }
    }

    float4 b0 = *reinterpret_cast<const float4*>(&bias[c0]);
    float4 b1 = *reinterpret_cast<const float4*>(&bias[c0 + 4]);
    float bv[8] = {b0.x, b0.y, b0.z, b0.w, b1.x, b1.y, b1.z, b1.w};
    float cs[8], cq[8];
#pragma unroll
    for (int j = 0; j < 8; ++j) { cs[j] = 0.f; cq[j] = 0.f; }
#pragma unroll
    for (int i = 0; i < 4; ++i) {
#pragma unroll
        for (int j = 0; j < 8; ++j) {
            float v = acc[i][j] + bv[j];
            acc[i][j] = v;
            cs[j] += v;
            cq[j] += v * v;
        }
    }
#pragma unroll
    for (int i = 0; i < 4; ++i) {
        size_t row = rowBase + i;
        float4 o0, o1;
        o0.x = acc[i][0]; o0.y = acc[i][1]; o0.z = acc[i][2]; o0.w = acc[i][3];
        o1.x = acc[i][4]; o1.y = acc[i][5]; o1.z = acc[i][6]; o1.w = acc[i][7];
        *reinterpret_cast<float4*>(&hout[row * D + c0])     = o0;
        *reinterpret_cast<float4*>(&hout[row * D + c0 + 4]) = o1;
    }
    // reduce cs/cq across the 4 rs-slots within the wave (lanes ^16, ^32)
#pragma unroll
    for (int j = 0; j < 8; ++j) {
        cs[j] += __shfl_xor(cs[j], 16, 64); cq[j] += __shfl_xor(cq[j], 16, 64);
        cs[j] += __shfl_xor(cs[j], 32, 64); cq[j] += __shfl_xor(cq[j], 32, 64);
    }
    __syncthreads();                     // Wl now reusable
    float* red = &Wl[0][0];              // 8 waves x 256 floats = 8 KB
    int wid = t >> 6, lane = t & 63;
    if (lane < 16) {
#pragma unroll
        for (int j = 0; j < 8; ++j) {
            red[wid * 256 + lane * 16 + j]     = cs[j];
            red[wid * 256 + lane * 16 + 8 + j] = cq[j];
        }
    }
    __syncthreads();
    if (t < 256) {
        float s = 0.f;
#pragma unroll
        for (int w = 0; w < 8; ++w) s += red[w * 256 + t];
        int cgi = t >> 4, r = t & 15;
        int ch = cgi * 8 + (r & 7);
        atomicAdd(&bnsums[(r < 8 ? 0 : D) + ch], s);
    }
}

// ---------------- BatchNorm finalize + apply ----------------

__global__ void bn_final(const float* __restrict__ sums, const float* __restrict__ g,
                         const float* __restrict__ bt, float* __restrict__ sc,
                         float* __restrict__ sh, int N) {
    int c = threadIdx.x;
    if (c >= D) return;
    float mu  = sums[c] / (float)N;
    float var = sums[D + c] / (float)N - mu * mu;
    float inv = rsqrtf(var + EPS);
    float scale = g[c] * inv;
    sc[c] = scale;
    sh[c] = bt[c] - mu * scale;
}

__global__ __launch_bounds__(256) void bn_apply_relu_max(float* __restrict__ h,
        const float* __restrict__ sc, const float* __restrict__ sh,
        float* __restrict__ nodemax, int N) {
    int node = (blockIdx.x * 256 + threadIdx.x) >> 5;
    int l = threadIdx.x & 31;
    if (node >= N) return;
    float4 v = *reinterpret_cast<const float4*>(h + (size_t)node * D + 4 * l);
    float4 a = *reinterpret_cast<const float4*>(sc + 4 * l);
    float4 b = *reinterpret_cast<const float4*>(sh + 4 * l);
    v.x = fmaxf(fmaf(v.x, a.x, b.x), 0.f);
    v.y = fmaxf(fmaf(v.y, a.y, b.y), 0.f);
    v.z = fmaxf(fmaf(v.z, a.z, b.z), 0.f);
    v.w = fmaxf(fmaf(v.w, a.w, b.w), 0.f);
    *reinterpret_cast<float4*>(h + (size_t)node * D + 4 * l) = v;
    float m = fmaxf(fmaxf(v.x, v.y), fmaxf(v.z, v.w));
#pragma unroll
    for (int d = 16; d > 0; d >>= 1) m = fmaxf(m, __shfl_xor(m, d, 64));
    if (l == 0) nodemax[node] = m;
}

__global__ __launch_bounds__(256) void rowmax_kernel(const float* __restrict__ h,
                                                     float* __restrict__ nodemax, int N) {
    int node = (blockIdx.x * 256 + threadIdx.x) >> 5;
    int l = threadIdx.x & 31;
    if (node >= N) return;
    float4 v = *reinterpret_cast<const float4*>(h + (size_t)node * D + 4 * l);
    float m = fmaxf(fmaxf(v.x, v.y), fmaxf(v.z, v.w));
#pragma unroll
    for (int d = 16; d > 0; d >>= 1) m = fmaxf(m, __shfl_xor(m, d, 64));
    if (l == 0) nodemax[node] = m;
}

// ---------------- SortPool top-k + head ----------------

__global__ __launch_bounds__(256) void topk_kernel(const float* __restrict__ nodemax,
                                                   int* __restrict__ tk, int NPG) {
    int g = blockIdx.x;
    int t = threadIdx.x;
    __shared__ float ov[256];
    __shared__ float sv[256];
    __shared__ int   si[256];
    ov[t] = (t < NPG) ? nodemax[(size_t)g * NPG + t] : -3.4e38f;
    __syncthreads();
    for (int sel = 0; sel < 3; ++sel) {
        sv[t] = ov[t]; si[t] = t;
        __syncthreads();
        for (int s = 128; s > 0; s >>= 1) {
            if (t < s) {
                float a = sv[t], b = sv[t + s];
                int ia = si[t], ib = si[t + s];
                if (b > a || (b == a && ib < ia)) { sv[t] = b; si[t] = ib; }
            }
            __syncthreads();
        }
        if (t == 0) {
            tk[g * 3 + sel] = g * NPG + si[0];
            ov[si[0]] = -3.4e38f;
        }
        __syncthreads();
    }
}

__global__ void score_init(float* __restrict__ score, const float* __restrict__ b0,
                           const float* __restrict__ b1, const float* __restrict__ b2,
                           const float* __restrict__ b3, int G) {
    int i = blockIdx.x * blockDim.x + threadIdx.x;
    if (i >= G * NCLS) return;
    int c = i % NCLS;
    score[i] = b0[c] + b1[c] + b2[c] + b3[c];
}

// one block (128 thr) per (graph, k): sort node features asc, dot with Pw rows
__global__ __launch_bounds__(128) void sort_head(const float* __restrict__ h,
        const int* __restrict__ tk, const float* __restrict__ Pw,
        float* __restrict__ score, int G) {
    int b = blockIdx.x;
    int g = b / KTOP, k = b - g * KTOP;
    int node = tk[b];
    int t = threadIdx.x;
    __shared__ float s[D];
    __shared__ float red[2][NCLS];
    s[t] = h[(size_t)node * D + t];
    __syncthreads();
    for (int size = 2; size <= D; size <<= 1) {
        for (int stride = size >> 1; stride > 0; stride >>= 1) {
            int ixj = t ^ stride;
            if (ixj > t) {
                float a = s[t], c = s[ixj];
                bool up = ((t & size) == 0);
                if ((a > c) == up) { s[t] = c; s[ixj] = a; }
            }
            __syncthreads();
        }
    }
    float v = s[t];
    const float* pw = Pw + (size_t)(k * D + t) * NCLS;
    float part[NCLS];
#pragma unroll
    for (int c = 0; c < NCLS; ++c) part[c] = v * pw[c];
    int lane = t & 63, wid = t >> 6;
#pragma unroll
    for (int c = 0; c < NCLS; ++c) {
        float x = part[c];
#pragma unroll
        for (int o = 32; o > 0; o >>= 1) x += __shfl_down(x, o, 64);
        if (lane == 0) red[wid][c] = x;
    }
    __syncthreads();
    if (t < NCLS) atomicAdd(&score[g * NCLS + t], red[0][t] + red[1][t]);
}

// ---------------- launch ----------------

extern "C" void kernel_launch(void* const* d_in, const int* in_sizes, int n_in,
                              void* d_out, int out_size, void* d_ws, size_t ws_size,
                              hipStream_t stream) {
    const float* x   = (const float*)d_in[0];
    const int*   src = (const int*)d_in[1];
    const int*   dst = (const int*)d_in[2];
    const float* W[3]  = {(const float*)d_in[5],  (const float*)d_in[9],  (const float*)d_in[13]};
    const float* bb[3] = {(const float*)d_in[6],  (const float*)d_in[10], (const float*)d_in[14]};
    const float* gg[3] = {(const float*)d_in[7],  (const float*)d_in[11], (const float*)d_in[15]};
    const float* bt[3] = {(const float*)d_in[8],  (const float*)d_in[12], (const float*)d_in[16]};
    const float* Pw[4] = {(const float*)d_in[17], (const float*)d_in[19], (const float*)d_in[21], (const float*)d_in[23]};
    const float* Pb[4] = {(const float*)d_in[18], (const float*)d_in[20], (const float*)d_in[22], (const float*)d_in[24]};

    int N = in_sizes[0] / D;
    int E = in_sizes[1];
    int G = out_size / NCLS;
    int NPG = N / G;
    float* score = (float*)d_out;

    size_t NF = (size_t)N * D;
    float* fws     = (float*)d_ws;
    float* H       = fws;
    float* T       = H + NF;
    float* rs_out  = T + NF;
    float* rs_in   = rs_out + N;
    float* nodemax = rs_in + N;
    float* bnsums  = nodemax + N;      // 3 layers x 2*D
    float* bscale  = bnsums + 6 * D;   // D
    float* bshift  = bscale + D;       // D
    int* deg_out = (int*)(bshift + D);
    int* deg_in  = deg_out + N;
    int* cursor  = deg_in + N;
    int* offs    = cursor + N;         // N+2 (padded for int2 alignment)
    int2* csrw   = (int2*)(offs + N + 2);  // E
    int* tk      = (int*)(csrw + E);   // G*3

    hipMemsetAsync(deg_out, 0, sizeof(int) * (size_t)3 * N, stream);  // deg_out, deg_in, cursor
    hipMemsetAsync(bnsums, 0, sizeof(float) * 6 * D, stream);
    deg_kernel<<<(E + 255) / 256, 256, 0, stream>>>(src, dst, deg_out, deg_in, E);
    rs_kernel<<<(N + 255) / 256, 256, 0, stream>>>(deg_out, deg_in, rs_out, rs_in, N);
    scan_kernel<<<1, 1024, 0, stream>>>(deg_in, offs, N);
    csr_scatter<<<(E + 255) / 256, 256, 0, stream>>>(src, dst, rs_out, offs, cursor, csrw, E);

    score_init<<<(G * NCLS + 255) / 256, 256, 0, stream>>>(score, Pb[0], Pb[1], Pb[2], Pb[3], G);

    // rep 0 head (raw x)
    rowmax_kernel<<<N / 8, 256, 0, stream>>>(x, nodemax, N);
    topk_kernel<<<G, 256, 0, stream>>>(nodemax, tk, NPG);
    sort_head<<<G * KTOP, D, 0, stream>>>(x, tk, Pw[0], score, G);

    const float* hin = x;
    for (int l = 0; l < 3; ++l) {
        float* bns = bnsums + l * 2 * D;
        aggregate_kernel<<<N / 8, 256, 0, stream>>>(hin, offs, csrw, rs_in, T, N);
        gemm_bn<<<N / GBM, 512, 0, stream>>>(T, W[l], bb[l], H, bns, N);
        bn_final<<<1, D, 0, stream>>>(bns, gg[l], bt[l], bscale, bshift, N);
        bn_apply_relu_max<<<N / 8, 256, 0, stream>>>(H, bscale, bshift, nodemax, N);
        topk_kernel<<<G, 256, 0, stream>>>(nodemax, tk, NPG);
        sort_head<<<G * KTOP, D, 0, stream>>>(H, tk, Pw[l + 1], score, G);
        hin = H;
    }
}

// Round 5
// 887.885 us; speedup vs baseline: 2.0608x; 1.1822x over previous
//
#include <hip/hip_runtime.h>
#include <hip/hip_bf16.h>

#define D 128
#define KTOP 3
#define NCLS 10
#define EPS 1e-5f
#define GBM 128   // rows per gemm block

// ---------------- degree / CSR build ----------------

__global__ void deg_kernel(const int* __restrict__ src, const int* __restrict__ dst,
                           int* __restrict__ deg_out, int* __restrict__ deg_in, int E) {
    int e = blockIdx.x * blockDim.x + threadIdx.x;
    if (e >= E) return;
    atomicAdd(&deg_out[src[e]], 1);
    atomicAdd(&deg_in[dst[e]], 1);
}

__global__ void rs_kernel(const int* __restrict__ deg_out, const int* __restrict__ deg_in,
                          float* __restrict__ rs_out, float* __restrict__ rs_in, int N) {
    int i = blockIdx.x * blockDim.x + threadIdx.x;
    if (i >= N) return;
    int a = deg_out[i]; if (a < 1) a = 1;
    int b = deg_in[i];  if (b < 1) b = 1;
    rs_out[i] = rsqrtf((float)a);
    rs_in[i]  = rsqrtf((float)b);
}

// ---- device-wide exclusive scan of deg_in -> offs[0..N] (3 kernels) ----

__global__ __launch_bounds__(1024) void scan_partial(const int* __restrict__ deg,
                                                     int* __restrict__ bsum, int N) {
    __shared__ int red[1024];
    int t = threadIdx.x;
    int i = blockIdx.x * 1024 + t;
    red[t] = (i < N) ? deg[i] : 0;
    __syncthreads();
    for (int s = 512; s > 0; s >>= 1) {
        if (t < s) red[t] += red[t + s];
        __syncthreads();
    }
    if (t == 0) bsum[blockIdx.x] = red[0];
}

__global__ __launch_bounds__(1024) void scan_bsum(const int* __restrict__ bsum,
                                                  int* __restrict__ bbase, int nb) {
    __shared__ int sh[1024];
    int t = threadIdx.x;
    sh[t] = (t < nb) ? bsum[t] : 0;
    __syncthreads();
    for (int off = 1; off < 1024; off <<= 1) {
        int v = (t >= off) ? sh[t - off] : 0;
        __syncthreads();
        sh[t] += v;
        __syncthreads();
    }
    if (t < nb) bbase[t] = (t == 0) ? 0 : sh[t - 1];
}

__global__ __launch_bounds__(1024) void scan_final(const int* __restrict__ deg,
                                                   const int* __restrict__ bbase,
                                                   int* __restrict__ offs, int N) {
    __shared__ int sh[1024];
    int t = threadIdx.x;
    int i = blockIdx.x * 1024 + t;
    int v = (i < N) ? deg[i] : 0;
    sh[t] = v;
    __syncthreads();
    for (int off = 1; off < 1024; off <<= 1) {
        int u = (t >= off) ? sh[t - off] : 0;
        __syncthreads();
        sh[t] += u;
        __syncthreads();
    }
    int excl = bbase[blockIdx.x] + sh[t] - v;
    if (i < N) offs[i] = excl;
    if (i == N - 1) offs[N] = excl + v;
}

// writes {src, bits(rs_out[src])} so the gather needs ONE 8B load per edge
__global__ void csr_scatter(const int* __restrict__ src, const int* __restrict__ dst,
                            const float* __restrict__ rs_out,
                            const int* __restrict__ offs, int* __restrict__ cursor,
                            int2* __restrict__ csrw, int E) {
    int e = blockIdx.x * blockDim.x + threadIdx.x;
    if (e >= E) return;
    int d = dst[e], s = src[e];
    int pos = offs[d] + atomicAdd(&cursor[d], 1);
    int2 p; p.x = s; p.y = __float_as_int(rs_out[s]);
    csrw[pos] = p;
}

// ---------------- aggregation: half-wave (32 lanes x float4) per node ----------------

__global__ __launch_bounds__(256) void aggregate_kernel(const float* __restrict__ hin,
        const int* __restrict__ offs, const int2* __restrict__ csrw,
        const float* __restrict__ rs_in, float* __restrict__ hout, int N) {
    int node = (blockIdx.x * 256 + threadIdx.x) >> 5;
    int l = threadIdx.x & 31;
    if (node >= N) return;
    int beg = offs[node], end = offs[node + 1];
    const float* base = hin + 4 * l;
    float ax0=0.f, ay0=0.f, az0=0.f, aw0=0.f;
    float ax1=0.f, ay1=0.f, az1=0.f, aw1=0.f;
    float ax2=0.f, ay2=0.f, az2=0.f, aw2=0.f;
    float ax3=0.f, ay3=0.f, az3=0.f, aw3=0.f;
    int nq = (end - beg) >> 2;
    int e = beg;
    int2 c0, c1, c2, c3;
    if (nq) { c0 = csrw[e]; c1 = csrw[e+1]; c2 = csrw[e+2]; c3 = csrw[e+3]; }
    for (int q = 0; q < nq; ++q) {
        int2 n0 = c0, n1 = c1, n2 = c2, n3 = c3;
        int en = e + 4;
        if (q + 1 < nq) { n0 = csrw[en]; n1 = csrw[en+1]; n2 = csrw[en+2]; n3 = csrw[en+3]; }
        float4 v0 = *reinterpret_cast<const float4*>(base + (size_t)c0.x * D);
        float4 v1 = *reinterpret_cast<const float4*>(base + (size_t)c1.x * D);
        float4 v2 = *reinterpret_cast<const float4*>(base + (size_t)c2.x * D);
        float4 v3 = *reinterpret_cast<const float4*>(base + (size_t)c3.x * D);
        float w0 = __int_as_float(c0.y), w1 = __int_as_float(c1.y);
        float w2 = __int_as_float(c2.y), w3 = __int_as_float(c3.y);
        ax0 += w0*v0.x; ay0 += w0*v0.y; az0 += w0*v0.z; aw0 += w0*v0.w;
        ax1 += w1*v1.x; ay1 += w1*v1.y; az1 += w1*v1.z; aw1 += w1*v1.w;
        ax2 += w2*v2.x; ay2 += w2*v2.y; az2 += w2*v2.z; aw2 += w2*v2.w;
        ax3 += w3*v3.x; ay3 += w3*v3.y; az3 += w3*v3.z; aw3 += w3*v3.w;
        c0 = n0; c1 = n1; c2 = n2; c3 = n3;
        e = en;
    }
    for (; e < end; ++e) {
        int2 c = csrw[e];
        float w = __int_as_float(c.y);
        float4 v = *reinterpret_cast<const float4*>(base + (size_t)c.x * D);
        ax0 += w*v.x; ay0 += w*v.y; az0 += w*v.z; aw0 += w*v.w;
    }
    float ri = rs_in[node];
    float4 r;
    r.x = ((ax0 + ax1) + (ax2 + ax3)) * ri;
    r.y = ((ay0 + ay1) + (ay2 + ay3)) * ri;
    r.z = ((az0 + az1) + (az2 + az3)) * ri;
    r.w = ((aw0 + aw1) + (aw2 + aw3)) * ri;
    *reinterpret_cast<float4*>(hout + (size_t)node * D + 4 * l) = r;
}

// ---------------- GEMM: W-in-LDS, A from global, fused bias + BN-stats ----------------

__global__ __launch_bounds__(512) void gemm_bn(const float* __restrict__ ain,
        const float* __restrict__ W, const float* __restrict__ bias,
        float* __restrict__ hout, float* __restrict__ bnsums, int N) {
    __shared__ __align__(16) float Wl[64][D];   // 32 KB
    int t = threadIdx.x;
    int cg = t & 15;
    int rs = t >> 4;
    int c0 = cg * 8;
    size_t rowBase = (size_t)blockIdx.x * GBM + 4 * rs;

    float acc[4][8];
#pragma unroll
    for (int i = 0; i < 4; ++i)
#pragma unroll
        for (int j = 0; j < 8; ++j) acc[i][j] = 0.f;

    for (int kc = 0; kc < D; kc += 64) {
        __syncthreads();
        const float4* Wv = reinterpret_cast<const float4*>(W + (size_t)kc * D);
        float4* Wd = reinterpret_cast<float4*>(&Wl[0][0]);
#pragma unroll
        for (int i = 0; i < 4; ++i) Wd[t + 512 * i] = Wv[t + 512 * i];
        __syncthreads();
#pragma unroll 2
        for (int k4 = 0; k4 < 16; ++k4) {
            const float* ap = ain + rowBase * D + kc + 4 * k4;
            float4 a0 = *reinterpret_cast<const float4*>(ap);
            float4 a1 = *reinterpret_cast<const float4*>(ap + D);
            float4 a2 = *reinterpret_cast<const float4*>(ap + 2 * D);
            float4 a3 = *reinterpret_cast<const float4*>(ap + 3 * D);
#pragma unroll
            for (int j = 0; j < 4; ++j) {
                int kk = 4 * k4 + j;
                float4 w0 = *reinterpret_cast<const float4*>(&Wl[kk][c0]);
                float4 w1 = *reinterpret_cast<const float4*>(&Wl[kk][c0 + 4]);
                float av[4];
                av[0] = (j==0)?a0.x:(j==1)?a0.y:(j==2)?a0.z:a0.w;
                av[1] = (j==0)?a1.x:(j==1)?a1.y:(j==2)?a1.z:a1.w;
                av[2] = (j==0)?a2.x:(j==1)?a2.y:(j==2)?a2.z:a2.w;
                av[3] = (j==0)?a3.x:(j==1)?a3.y:(j==2)?a3.z:a3.w;
                float wv[8] = {w0.x, w0.y, w0.z, w0.w, w1.x, w1.y, w1.z, w1.w};
#pragma unroll
                for (int i = 0; i < 4; ++i)
#pragma unroll
                    for (int jj = 0; jj < 8; ++jj) acc[i][jj] += av[i] * wv[jj];
            }
        }
    }

    float4 b0 = *reinterpret_cast<const float4*>(&bias[c0]);
    float4 b1 = *reinterpret_cast<const float4*>(&bias[c0 + 4]);
    float bv[8] = {b0.x, b0.y, b0.z, b0.w, b1.x, b1.y, b1.z, b1.w};
    float cs[8], cq[8];
#pragma unroll
    for (int j = 0; j < 8; ++j) { cs[j] = 0.f; cq[j] = 0.f; }
#pragma unroll
    for (int i = 0; i < 4; ++i) {
#pragma unroll
        for (int j = 0; j < 8; ++j) {
            float v = acc[i][j] + bv[j];
            acc[i][j] = v;
            cs[j] += v;
            cq[j] += v * v;
        }
    }
#pragma unroll
    for (int i = 0; i < 4; ++i) {
        size_t row = rowBase + i;
        float4 o0, o1;
        o0.x = acc[i][0]; o0.y = acc[i][1]; o0.z = acc[i][2]; o0.w = acc[i][3];
        o1.x = acc[i][4]; o1.y = acc[i][5]; o1.z = acc[i][6]; o1.w = acc[i][7];
        *reinterpret_cast<float4*>(&hout[row * D + c0])     = o0;
        *reinterpret_cast<float4*>(&hout[row * D + c0 + 4]) = o1;
    }
    // reduce cs/cq across the 4 rs-slots within the wave (lanes ^16, ^32)
#pragma unroll
    for (int j = 0; j < 8; ++j) {
        cs[j] += __shfl_xor(cs[j], 16, 64); cq[j] += __shfl_xor(cq[j], 16, 64);
        cs[j] += __shfl_xor(cs[j], 32, 64); cq[j] += __shfl_xor(cq[j], 32, 64);
    }
    __syncthreads();                     // Wl now reusable
    float* red = &Wl[0][0];              // 8 waves x 256 floats = 8 KB
    int wid = t >> 6, lane = t & 63;
    if (lane < 16) {
#pragma unroll
        for (int j = 0; j < 8; ++j) {
            red[wid * 256 + lane * 16 + j]     = cs[j];
            red[wid * 256 + lane * 16 + 8 + j] = cq[j];
        }
    }
    __syncthreads();
    if (t < 256) {
        float s = 0.f;
#pragma unroll
        for (int w = 0; w < 8; ++w) s += red[w * 256 + t];
        int cgi = t >> 4, r = t & 15;
        int ch = cgi * 8 + (r & 7);
        atomicAdd(&bnsums[(r < 8 ? 0 : D) + ch], s);
    }
}

// ---------------- BatchNorm finalize + apply ----------------

__global__ void bn_final(const float* __restrict__ sums, const float* __restrict__ g,
                         const float* __restrict__ bt, float* __restrict__ sc,
                         float* __restrict__ sh, int N) {
    int c = threadIdx.x;
    if (c >= D) return;
    float mu  = sums[c] / (float)N;
    float var = sums[D + c] / (float)N - mu * mu;
    float inv = rsqrtf(var + EPS);
    float scale = g[c] * inv;
    sc[c] = scale;
    sh[c] = bt[c] - mu * scale;
}

__global__ __launch_bounds__(256) void bn_apply_relu_max(float* __restrict__ h,
        const float* __restrict__ sc, const float* __restrict__ sh,
        float* __restrict__ nodemax, int N) {
    int node = (blockIdx.x * 256 + threadIdx.x) >> 5;
    int l = threadIdx.x & 31;
    if (node >= N) return;
    float4 v = *reinterpret_cast<const float4*>(h + (size_t)node * D + 4 * l);
    float4 a = *reinterpret_cast<const float4*>(sc + 4 * l);
    float4 b = *reinterpret_cast<const float4*>(sh + 4 * l);
    v.x = fmaxf(fmaf(v.x, a.x, b.x), 0.f);
    v.y = fmaxf(fmaf(v.y, a.y, b.y), 0.f);
    v.z = fmaxf(fmaf(v.z, a.z, b.z), 0.f);
    v.w = fmaxf(fmaf(v.w, a.w, b.w), 0.f);
    *reinterpret_cast<float4*>(h + (size_t)node * D + 4 * l) = v;
    float m = fmaxf(fmaxf(v.x, v.y), fmaxf(v.z, v.w));
#pragma unroll
    for (int d = 16; d > 0; d >>= 1) m = fmaxf(m, __shfl_xor(m, d, 64));
    if (l == 0) nodemax[node] = m;
}

__global__ __launch_bounds__(256) void rowmax_kernel(const float* __restrict__ h,
                                                     float* __restrict__ nodemax, int N) {
    int node = (blockIdx.x * 256 + threadIdx.x) >> 5;
    int l = threadIdx.x & 31;
    if (node >= N) return;
    float4 v = *reinterpret_cast<const float4*>(h + (size_t)node * D + 4 * l);
    float m = fmaxf(fmaxf(v.x, v.y), fmaxf(v.z, v.w));
#pragma unroll
    for (int d = 16; d > 0; d >>= 1) m = fmaxf(m, __shfl_xor(m, d, 64));
    if (l == 0) nodemax[node] = m;
}

// ---------------- SortPool top-k + head ----------------

__global__ __launch_bounds__(256) void topk_kernel(const float* __restrict__ nodemax,
                                                   int* __restrict__ tk, int NPG) {
    int g = blockIdx.x;
    int t = threadIdx.x;
    __shared__ float ov[256];
    __shared__ float sv[256];
    __shared__ int   si[256];
    ov[t] = (t < NPG) ? nodemax[(size_t)g * NPG + t] : -3.4e38f;
    __syncthreads();
    for (int sel = 0; sel < 3; ++sel) {
        sv[t] = ov[t]; si[t] = t;
        __syncthreads();
        for (int s = 128; s > 0; s >>= 1) {
            if (t < s) {
                float a = sv[t], b = sv[t + s];
                int ia = si[t], ib = si[t + s];
                if (b > a || (b == a && ib < ia)) { sv[t] = b; si[t] = ib; }
            }
            __syncthreads();
        }
        if (t == 0) {
            tk[g * 3 + sel] = g * NPG + si[0];
            ov[si[0]] = -3.4e38f;
        }
        __syncthreads();
    }
}

__global__ void score_init(float* __restrict__ score, const float* __restrict__ b0,
                           const float* __restrict__ b1, const float* __restrict__ b2,
                           const float* __restrict__ b3, int G) {
    int i = blockIdx.x * blockDim.x + threadIdx.x;
    if (i >= G * NCLS) return;
    int c = i % NCLS;
    score[i] = b0[c] + b1[c] + b2[c] + b3[c];
}

// one block (128 thr) per (graph, k): sort node features asc, dot with Pw rows
__global__ __launch_bounds__(128) void sort_head(const float* __restrict__ h,
        const int* __restrict__ tk, const float* __restrict__ Pw,
        float* __restrict__ score, int G) {
    int b = blockIdx.x;
    int g = b / KTOP, k = b - g * KTOP;
    int node = tk[b];
    int t = threadIdx.x;
    __shared__ float s[D];
    __shared__ float red[2][NCLS];
    s[t] = h[(size_t)node * D + t];
    __syncthreads();
    for (int size = 2; size <= D; size <<= 1) {
        for (int stride = size >> 1; stride > 0; stride >>= 1) {
            int ixj = t ^ stride;
            if (ixj > t) {
                float a = s[t], c = s[ixj];
                bool up = ((t & size) == 0);
                if ((a > c) == up) { s[t] = c; s[ixj] = a; }
            }
            __syncthreads();
        }
    }
    float v = s[t];
    const float* pw = Pw + (size_t)(k * D + t) * NCLS;
    float part[NCLS];
#pragma unroll
    for (int c = 0; c < NCLS; ++c) part[c] = v * pw[c];
    int lane = t & 63, wid = t >> 6;
#pragma unroll
    for (int c = 0; c < NCLS; ++c) {
        float x = part[c];
#pragma unroll
        for (int o = 32; o > 0; o >>= 1) x += __shfl_down(x, o, 64);
        if (lane == 0) red[wid][c] = x;
    }
    __syncthreads();
    if (t < NCLS) atomicAdd(&score[g * NCLS + t], red[0][t] + red[1][t]);
}

// ---------------- launch ----------------

extern "C" void kernel_launch(void* const* d_in, const int* in_sizes, int n_in,
                              void* d_out, int out_size, void* d_ws, size_t ws_size,
                              hipStream_t stream) {
    const float* x   = (const float*)d_in[0];
    const int*   src = (const int*)d_in[1];
    const int*   dst = (const int*)d_in[2];
    const float* W[3]  = {(const float*)d_in[5],  (const float*)d_in[9],  (const float*)d_in[13]};
    const float* bb[3] = {(const float*)d_in[6],  (const float*)d_in[10], (const float*)d_in[14]};
    const float* gg[3] = {(const float*)d_in[7],  (const float*)d_in[11], (const float*)d_in[15]};
    const float* bt[3] = {(const float*)d_in[8],  (const float*)d_in[12], (const float*)d_in[16]};
    const float* Pw[4] = {(const float*)d_in[17], (const float*)d_in[19], (const float*)d_in[21], (const float*)d_in[23]};
    const float* Pb[4] = {(const float*)d_in[18], (const float*)d_in[20], (const float*)d_in[22], (const float*)d_in[24]};

    int N = in_sizes[0] / D;
    int E = in_sizes[1];
    int G = out_size / NCLS;
    int NPG = N / G;
    float* score = (float*)d_out;

    size_t NF = (size_t)N * D;
    float* fws     = (float*)d_ws;
    float* H       = fws;
    float* T       = H + NF;
    float* rs_out  = T + NF;
    float* rs_in   = rs_out + N;
    float* nodemax = rs_in + N;
    float* bnsums  = nodemax + N;      // 3 layers x 2*D
    float* bscale  = bnsums + 6 * D;   // D
    float* bshift  = bscale + D;       // D
    int* deg_out = (int*)(bshift + D);
    int* deg_in  = deg_out + N;
    int* cursor  = deg_in + N;
    int* offs    = cursor + N;         // N+2 (padded for int2 alignment)
    int* bsum    = offs + N + 2;       // nb
    int* bbase   = bsum + 1024;        // nb
    int2* csrw   = (int2*)(bbase + 1024);  // E
    int* tk      = (int*)(csrw + E);   // G*3

    int nb = (N + 1023) >> 10;

    hipMemsetAsync(deg_out, 0, sizeof(int) * (size_t)3 * N, stream);  // deg_out, deg_in, cursor
    hipMemsetAsync(bnsums, 0, sizeof(float) * 6 * D, stream);
    deg_kernel<<<(E + 255) / 256, 256, 0, stream>>>(src, dst, deg_out, deg_in, E);
    rs_kernel<<<(N + 255) / 256, 256, 0, stream>>>(deg_out, deg_in, rs_out, rs_in, N);
    scan_partial<<<nb, 1024, 0, stream>>>(deg_in, bsum, N);
    scan_bsum<<<1, 1024, 0, stream>>>(bsum, bbase, nb);
    scan_final<<<nb, 1024, 0, stream>>>(deg_in, bbase, offs, N);
    csr_scatter<<<(E + 255) / 256, 256, 0, stream>>>(src, dst, rs_out, offs, cursor, csrw, E);

    score_init<<<(G * NCLS + 255) / 256, 256, 0, stream>>>(score, Pb[0], Pb[1], Pb[2], Pb[3], G);

    // rep 0 head (raw x)
    rowmax_kernel<<<N / 8, 256, 0, stream>>>(x, nodemax, N);
    topk_kernel<<<G, 256, 0, stream>>>(nodemax, tk, NPG);
    sort_head<<<G * KTOP, D, 0, stream>>>(x, tk, Pw[0], score, G);

    const float* hin = x;
    for (int l = 0; l < 3; ++l) {
        float* bns = bnsums + l * 2 * D;
        aggregate_kernel<<<N / 8, 256, 0, stream>>>(hin, offs, csrw, rs_in, T, N);
        gemm_bn<<<N / GBM, 512, 0, stream>>>(T, W[l], bb[l], H, bns, N);
        bn_final<<<1, D, 0, stream>>>(bns, gg[l], bt[l], bscale, bshift, N);
        bn_apply_relu_max<<<N / 8, 256, 0, stream>>>(H, bscale, bshift, nodemax, N);
        topk_kernel<<<G, 256, 0, stream>>>(nodemax, tk, NPG);
        sort_head<<<G * KTOP, D, 0, stream>>>(H, tk, Pw[l + 1], score, G);
        hin = H;
    }
}